// Round 2
// baseline (230.833 us; speedup 1.0000x reference)
//
#include <hip/hip_runtime.h>

// LIF scan over T=8, N=4.2M float4-sites. History:
//  - Prev session R1-7: schedules w/ CACHED loads -> all 87-95 us kernel.
//  - Prev R8: NT loads + NT stores -> kernel < 80 us (below poison fills).
//  - R0 this session: NT loads + cached stores -> 230.16 us harness,
//    EXACTLY neutral vs NT stores. Cache-policy 2x2 complete: only NT
//    LOADS matter. Store policy irrelevant.
//  - This round: schedule x NT-load interaction (untested; prev schedule
//    experiments were all cached-load). Burst-load all 8 x[t] (NT),
//    run the serial LIF chain in registers, burst-store all 8 s[t].
//    Per-wave pure-read phase then pure-write phase -> coarsen global
//    HBM read/write turnaround from per-instruction to per-phase.
//    Predict kernel -10-20 us, harness 230 -> 212-222. If neutral:
//    service-rate ceiling for mixed 268 MB stream -> roofline.

typedef float v4f __attribute__((ext_vector_type(4)));

#define DECAY  0.25f
#define THRESH 0.5f

__global__ __launch_bounds__(256) void lif_scan_kernel(
    const v4f* __restrict__ x, v4f* __restrict__ out, int n4) {
    const int i = blockIdx.x * blockDim.x + threadIdx.x;
    if (i >= n4) return;

    const size_t idx = (size_t)i;
    const size_t st  = (size_t)n4;

    // ---- burst: issue all 8 NT loads back-to-back (independent addrs) ----
    v4f x0 = __builtin_nontemporal_load(&x[idx + 0 * st]);
    v4f x1 = __builtin_nontemporal_load(&x[idx + 1 * st]);
    v4f x2 = __builtin_nontemporal_load(&x[idx + 2 * st]);
    v4f x3 = __builtin_nontemporal_load(&x[idx + 3 * st]);
    v4f x4 = __builtin_nontemporal_load(&x[idx + 4 * st]);
    v4f x5 = __builtin_nontemporal_load(&x[idx + 5 * st]);
    v4f x6 = __builtin_nontemporal_load(&x[idx + 6 * st]);
    v4f x7 = __builtin_nontemporal_load(&x[idx + 7 * st]);

    // ---- serial LIF chain, all in registers ----
    v4f m = {0.f, 0.f, 0.f, 0.f};
    v4f s = {0.f, 0.f, 0.f, 0.f};
    v4f s0, s1, s2, s3, s4, s5, s6, s7;

#define STEP(XV, SV)                                        \
    m[0] = m[0] * (DECAY * (1.f - s[0])) + (XV)[0];         \
    m[1] = m[1] * (DECAY * (1.f - s[1])) + (XV)[1];         \
    m[2] = m[2] * (DECAY * (1.f - s[2])) + (XV)[2];         \
    m[3] = m[3] * (DECAY * (1.f - s[3])) + (XV)[3];         \
    s[0] = (m[0] >= THRESH) ? 1.f : 0.f;                    \
    s[1] = (m[1] >= THRESH) ? 1.f : 0.f;                    \
    s[2] = (m[2] >= THRESH) ? 1.f : 0.f;                    \
    s[3] = (m[3] >= THRESH) ? 1.f : 0.f;                    \
    (SV) = s;

    STEP(x0, s0) STEP(x1, s1) STEP(x2, s2) STEP(x3, s3)
    STEP(x4, s4) STEP(x5, s5) STEP(x6, s6) STEP(x7, s7)
#undef STEP

    // ---- burst: all 8 NT stores back-to-back ----
    __builtin_nontemporal_store(s0, &out[idx + 0 * st]);
    __builtin_nontemporal_store(s1, &out[idx + 1 * st]);
    __builtin_nontemporal_store(s2, &out[idx + 2 * st]);
    __builtin_nontemporal_store(s3, &out[idx + 3 * st]);
    __builtin_nontemporal_store(s4, &out[idx + 4 * st]);
    __builtin_nontemporal_store(s5, &out[idx + 5 * st]);
    __builtin_nontemporal_store(s6, &out[idx + 6 * st]);
    __builtin_nontemporal_store(s7, &out[idx + 7 * st]);
}

extern "C" void kernel_launch(void* const* d_in, const int* in_sizes, int n_in,
                              void* d_out, int out_size, void* d_ws, size_t ws_size,
                              hipStream_t stream) {
    const float* x = (const float*)d_in[0];
    float* out = (float*)d_out;

    const int total = in_sizes[0];        // 8 * 32 * 128 * 32 * 32 = 33,554,432
    const int T = 8;
    const int n = total / T;              // 4,194,304 sites per timestep
    const int n4 = n / 4;                 // 1,048,576 float4 groups

    const int block = 256;
    const int grid = (n4 + block - 1) / block;  // 4096 blocks, exact

    lif_scan_kernel<<<grid, block, 0, stream>>>(
        (const v4f*)x, (v4f*)out, n4);
}